// Round 2
// baseline (180.567 us; speedup 1.0000x reference)
//
#include <hip/hip_runtime.h>

// VQ quantizer: z [8,8,16,64,64] f32, codebook [512,8] f32
// outputs concat: z_q_st (4194304 f32) | vq_loss (1 f32) | idx (524288 f32-valued)
//
// R2: P=4 points/thread + packed-fp32 (v_pk_fma_f32 via float2 elementwise fma)
// distance loop. Each pk half is an independent IEEE fp32 fma -> np-bit-exact.

#define NPTS      524288      // 8*16*64*64
#define KCODES    512
#define DDIM      8
#define CH_STRIDE 65536       // T*H*W
#define B_STRIDE  524288      // D*T*H*W
#define PPT       4           // points per thread
#define BLK       256
#define REC       12          // packed record: c0..c7, e2, 3 pad (48B, 16B-aligned)

typedef float v2f __attribute__((ext_vector_type(2)));

// numpy pairwise-sum tree for n=8: ((x0+x1)+(x2+x3)) + ((x4+x5)+(x6+x7)),
// products rounded separately (no fma).
__device__ __forceinline__ float np_sumsq8(const float* x) {
    float p0 = __fmul_rn(x[0], x[0]);
    float p1 = __fmul_rn(x[1], x[1]);
    float p2 = __fmul_rn(x[2], x[2]);
    float p3 = __fmul_rn(x[3], x[3]);
    float p4 = __fmul_rn(x[4], x[4]);
    float p5 = __fmul_rn(x[5], x[5]);
    float p6 = __fmul_rn(x[6], x[6]);
    float p7 = __fmul_rn(x[7], x[7]);
    return __fadd_rn(__fadd_rn(__fadd_rn(p0, p1), __fadd_rn(p2, p3)),
                     __fadd_rn(__fadd_rn(p4, p5), __fadd_rn(p6, p7)));
}

// Build packed record array in d_ws: pk[k*12 + {0..7}] = code, [8] = e2, [9..11] pad.
__global__ void prep_packed(const float* __restrict__ cb, float* __restrict__ pk) {
    int k = threadIdx.x;  // 512 threads, 1 block
    if (k >= KCODES) return;
    float c[DDIM];
    #pragma unroll
    for (int j = 0; j < DDIM; ++j) c[j] = cb[k * DDIM + j];
    float* r = pk + (size_t)k * REC;
    #pragma unroll
    for (int j = 0; j < DDIM; ++j) r[j] = c[j];
    r[8] = np_sumsq8(c);
    r[9] = 0.0f; r[10] = 0.0f; r[11] = 0.0f;
}

__global__ __launch_bounds__(BLK) void vq_main(
    const float* __restrict__ z, const float* __restrict__ pk,
    float* __restrict__ out_zq, float* __restrict__ out_loss,
    float* __restrict__ out_idx)
{
    const int base = blockIdx.x * (BLK * PPT) + threadIdx.x;

    float zv[PPT][DDIM];
    float z2s[PPT];
    #pragma unroll
    for (int p = 0; p < PPT; ++p) {
        const int n = base + p * BLK;
        const int b = n >> 16;
        const int s = n & 65535;
        const float* zp = z + (size_t)b * B_STRIDE + s;
        #pragma unroll
        for (int j = 0; j < DDIM; ++j) zv[p][j] = zp[(size_t)j * CH_STRIDE];
        z2s[p] = np_sumsq8(zv[p]);
    }

    // pair points (0,1) and (2,3) into float2 register pairs
    v2f zA[DDIM], zB[DDIM];
    #pragma unroll
    for (int j = 0; j < DDIM; ++j) {
        zA[j] = (v2f){zv[0][j], zv[1][j]};
        zB[j] = (v2f){zv[2][j], zv[3][j]};
    }
    const v2f z2A = (v2f){z2s[0], z2s[1]};
    const v2f z2B = (v2f){z2s[2], z2s[3]};
    const v2f m2  = (v2f){-2.0f, -2.0f};

    float dm0 = 3.402823466e+38f, dm1 = dm0, dm2 = dm0, dm3 = dm0;
    int   i0 = 0, i1 = 0, i2 = 0, i3 = 0;

    #pragma unroll 4
    for (int k = 0; k < KCODES; ++k) {
        const float4* rec = (const float4*)(pk + (size_t)k * REC);
        const float4 r0 = rec[0];
        const float4 r1 = rec[1];
        const float4 r2 = rec[2];
        const float cc[DDIM] = {r0.x, r0.y, r0.z, r0.w, r1.x, r1.y, r1.z, r1.w};

        v2f zeA = (v2f){0.0f, 0.0f};
        v2f zeB = (v2f){0.0f, 0.0f};
        #pragma unroll
        for (int j = 0; j < DDIM; ++j) {
            const v2f cj = (v2f){cc[j], cc[j]};
            // np (OpenBLAS) sequential ascending-k fma chain, per half
            zeA = __builtin_elementwise_fma(zA[j], cj, zeA);
            zeB = __builtin_elementwise_fma(zB[j], cj, zeB);
        }
        const v2f e2v = (v2f){r2.x, r2.x};
        const v2f tA = z2A + e2v;   // np: z2 + e2 (plain IEEE add per half)
        const v2f tB = z2B + e2v;
        const v2f dA = __builtin_elementwise_fma(m2, zeA, tA);  // np: t - 2*ze
        const v2f dB = __builtin_elementwise_fma(m2, zeB, tB);

        if (dA.x < dm0) { dm0 = dA.x; i0 = k; }   // strict <: np first-min
        if (dA.y < dm1) { dm1 = dA.y; i1 = k; }
        if (dB.x < dm2) { dm2 = dB.x; i2 = k; }
        if (dB.y < dm3) { dm3 = dB.y; i3 = k; }
    }

    const int im[PPT] = {i0, i1, i2, i3};
    float lsum = 0.0f;
    #pragma unroll
    for (int p = 0; p < PPT; ++p) {
        const int n = base + p * BLK;
        const int b = n >> 16;
        const int s = n & 65535;
        const float* cw = pk + (size_t)im[p] * REC;
        float* op = out_zq + (size_t)b * B_STRIDE + s;
        #pragma unroll
        for (int j = 0; j < DDIM; ++j) {
            const float zq = cw[j];
            const float t  = __fsub_rn(zq, zv[p][j]);           // np: z_q - z
            op[(size_t)j * CH_STRIDE] = __fadd_rn(zv[p][j], t); // np: z + (z_q - z)
            lsum = __fmaf_rn(t, t, lsum);                       // loss (2% tol)
        }
        out_idx[n] = (float)im[p];
    }

    // block reduction of loss partials: wave shuffle -> LDS -> one atomic/block
    #pragma unroll
    for (int off = 32; off > 0; off >>= 1) lsum += __shfl_down(lsum, off, 64);
    __shared__ float wsum[4];
    const int lane = threadIdx.x & 63;
    const int wid  = threadIdx.x >> 6;
    if (lane == 0) wsum[wid] = lsum;
    __syncthreads();
    if (threadIdx.x == 0) {
        float bs = ((wsum[0] + wsum[1]) + (wsum[2] + wsum[3]));
        // vq_loss = codebk + BETA*commit = 1.25 * mean((z_q - z)^2)
        atomicAdd(out_loss, bs * (1.25f / 4194304.0f));
    }
}

extern "C" void kernel_launch(void* const* d_in, const int* in_sizes, int n_in,
                              void* d_out, int out_size, void* d_ws, size_t ws_size,
                              hipStream_t stream) {
    const float* z  = (const float*)d_in[0];
    const float* cb = (const float*)d_in[1];
    float* out      = (float*)d_out;
    float* out_zq   = out;                    // 4194304 elems
    float* out_loss = out + 4194304;          // 1 elem
    float* out_idx  = out + 4194305;          // 524288 elems (as float values)
    float* pk       = (float*)d_ws;           // 512*12 floats packed records

    hipMemsetAsync(out_loss, 0, sizeof(float), stream);
    prep_packed<<<1, 512, 0, stream>>>(cb, pk);
    vq_main<<<NPTS / (BLK * PPT), BLK, 0, stream>>>(z, pk, out_zq, out_loss, out_idx);
}

// Round 3
// 157.755 us; speedup vs baseline: 1.1446x; 1.1446x over previous
//
#include <hip/hip_runtime.h>

// VQ quantizer: z [8,8,16,64,64] f32, codebook [512,8] f32
// outputs concat: z_q_st (4194304 f32) | vq_loss (1 f32) | idx (524288 f32-valued)
//
// R3: code-pair packed records (dup layout, 80B: c0a,c0b,...,c7a,c7b,e2a,e2b,pad2),
// P=2 points/thread (4 waves/SIMD), register double-buffered record loads.
// Each pk half = independent IEEE fp32 op -> np-bit-exact (validated R1/R2 absmax 0).

#define NPTS      524288      // 8*16*64*64
#define KCODES    512
#define NPAIRS    256
#define DDIM      8
#define CH_STRIDE 65536       // T*H*W
#define B_STRIDE  524288      // D*T*H*W
#define PPT       2           // points per thread
#define BLK       256
#define RECF      20          // floats per pair record (80B = 5 float4)

typedef float v2f __attribute__((ext_vector_type(2)));

__device__ __forceinline__ v2f lo2(float4 f) { return (v2f){f.x, f.y}; }
__device__ __forceinline__ v2f hi2(float4 f) { return (v2f){f.z, f.w}; }

// numpy pairwise-sum tree for n=8: ((x0+x1)+(x2+x3)) + ((x4+x5)+(x6+x7)),
// products rounded separately (no fma).
__device__ __forceinline__ float np_sumsq8(const float* x) {
    float p0 = __fmul_rn(x[0], x[0]);
    float p1 = __fmul_rn(x[1], x[1]);
    float p2 = __fmul_rn(x[2], x[2]);
    float p3 = __fmul_rn(x[3], x[3]);
    float p4 = __fmul_rn(x[4], x[4]);
    float p5 = __fmul_rn(x[5], x[5]);
    float p6 = __fmul_rn(x[6], x[6]);
    float p7 = __fmul_rn(x[7], x[7]);
    return __fadd_rn(__fadd_rn(__fadd_rn(p0, p1), __fadd_rn(p2, p3)),
                     __fadd_rn(__fadd_rn(p4, p5), __fadd_rn(p6, p7)));
}

// Build pair records: rec g = codes (2g, 2g+1) interleaved + e2 pair + pad.
__global__ void prep_pairs(const float* __restrict__ cb, float* __restrict__ pk) {
    int g = threadIdx.x;  // 256 threads, 1 block
    if (g >= NPAIRS) return;
    float a[DDIM], b[DDIM];
    #pragma unroll
    for (int j = 0; j < DDIM; ++j) {
        a[j] = cb[(2 * g) * DDIM + j];
        b[j] = cb[(2 * g + 1) * DDIM + j];
    }
    float* r = pk + (size_t)g * RECF;
    #pragma unroll
    for (int j = 0; j < DDIM; ++j) { r[2 * j] = a[j]; r[2 * j + 1] = b[j]; }
    r[16] = np_sumsq8(a);
    r[17] = np_sumsq8(b);
    r[18] = 0.0f; r[19] = 0.0f;
}

__global__ __launch_bounds__(BLK, 4) void vq_main(
    const float* __restrict__ z, const float* __restrict__ pk,
    float* __restrict__ out_zq, float* __restrict__ out_loss,
    float* __restrict__ out_idx)
{
    const int base = blockIdx.x * (BLK * PPT) + threadIdx.x;

    // load P=2 points, duplicate each z element into both pk halves (loop-invariant)
    v2f zd[PPT][DDIM];
    v2f z2d[PPT];
    #pragma unroll
    for (int p = 0; p < PPT; ++p) {
        const int n = base + p * BLK;
        const int b = n >> 16;
        const int s = n & 65535;
        const float* zp = z + (size_t)b * B_STRIDE + s;
        float tmp[DDIM];
        #pragma unroll
        for (int j = 0; j < DDIM; ++j) {
            tmp[j] = zp[(size_t)j * CH_STRIDE];
            zd[p][j] = (v2f){tmp[j], tmp[j]};
        }
        const float z2 = np_sumsq8(tmp);
        z2d[p] = (v2f){z2, z2};
    }

    const v2f m2 = (v2f){-2.0f, -2.0f};
    float dm0 = 3.402823466e+38f, dm1 = 3.402823466e+38f;
    int   i0 = 0, i1 = 0;

    const float4* recs = (const float4*)pk;  // 5 float4 per pair record
    float4 cur[5];
    #pragma unroll
    for (int q = 0; q < 5; ++q) cur[q] = recs[q];

    #pragma unroll 2
    for (int g = 0; g < NPAIRS; ++g) {
        // prefetch next record (wrap reload of rec 0 on last iter: harmless)
        const int gn = (g + 1) & (NPAIRS - 1);
        float4 nxt[5];
        #pragma unroll
        for (int q = 0; q < 5; ++q) nxt[q] = recs[gn * 5 + q];

        // unpack current record into v2f views (register renames, no movs)
        const v2f cp0 = lo2(cur[0]), cp1 = hi2(cur[0]);
        const v2f cp2 = lo2(cur[1]), cp3 = hi2(cur[1]);
        const v2f cp4 = lo2(cur[2]), cp5 = hi2(cur[2]);
        const v2f cp6 = lo2(cur[3]), cp7 = hi2(cur[3]);
        const v2f e2p = lo2(cur[4]);

        // np (OpenBLAS) sequential ascending-j fma chain from 0, per half
        v2f ze0 = (v2f){0.0f, 0.0f};
        v2f ze1 = (v2f){0.0f, 0.0f};
        ze0 = __builtin_elementwise_fma(zd[0][0], cp0, ze0);
        ze1 = __builtin_elementwise_fma(zd[1][0], cp0, ze1);
        ze0 = __builtin_elementwise_fma(zd[0][1], cp1, ze0);
        ze1 = __builtin_elementwise_fma(zd[1][1], cp1, ze1);
        ze0 = __builtin_elementwise_fma(zd[0][2], cp2, ze0);
        ze1 = __builtin_elementwise_fma(zd[1][2], cp2, ze1);
        ze0 = __builtin_elementwise_fma(zd[0][3], cp3, ze0);
        ze1 = __builtin_elementwise_fma(zd[1][3], cp3, ze1);
        ze0 = __builtin_elementwise_fma(zd[0][4], cp4, ze0);
        ze1 = __builtin_elementwise_fma(zd[1][4], cp4, ze1);
        ze0 = __builtin_elementwise_fma(zd[0][5], cp5, ze0);
        ze1 = __builtin_elementwise_fma(zd[1][5], cp5, ze1);
        ze0 = __builtin_elementwise_fma(zd[0][6], cp6, ze0);
        ze1 = __builtin_elementwise_fma(zd[1][6], cp6, ze1);
        ze0 = __builtin_elementwise_fma(zd[0][7], cp7, ze0);
        ze1 = __builtin_elementwise_fma(zd[1][7], cp7, ze1);

        const v2f t0 = z2d[0] + e2p;                        // np: z2 + e2
        const v2f t1 = z2d[1] + e2p;
        const v2f d0 = __builtin_elementwise_fma(m2, ze0, t0);  // np: t - 2*ze (2*ze exact)
        const v2f d1 = __builtin_elementwise_fma(m2, ze1, t1);

        const int k0 = 2 * g, k1 = 2 * g + 1;
        // strict <, even code before odd: np first-min tie-break
        if (d0.x < dm0) { dm0 = d0.x; i0 = k0; }
        if (d0.y < dm0) { dm0 = d0.y; i0 = k1; }
        if (d1.x < dm1) { dm1 = d1.x; i1 = k0; }
        if (d1.y < dm1) { dm1 = d1.y; i1 = k1; }

        #pragma unroll
        for (int q = 0; q < 5; ++q) cur[q] = nxt[q];
    }

    const int im[PPT] = {i0, i1};
    float lsum = 0.0f;
    #pragma unroll
    for (int p = 0; p < PPT; ++p) {
        const int n = base + p * BLK;
        const int b = n >> 16;
        const int s = n & 65535;
        const float* cw = pk + (size_t)(im[p] >> 1) * RECF + (im[p] & 1);
        float* op = out_zq + (size_t)b * B_STRIDE + s;
        #pragma unroll
        for (int j = 0; j < DDIM; ++j) {
            const float zq = cw[2 * j];
            const float zvj = zd[p][j].x;
            const float t = __fsub_rn(zq, zvj);            // np: z_q - z
            op[(size_t)j * CH_STRIDE] = __fadd_rn(zvj, t); // np: z + (z_q - z)
            lsum = __fmaf_rn(t, t, lsum);                  // loss (2% tol)
        }
        out_idx[n] = (float)im[p];
    }

    // block reduction of loss partials: wave shuffle -> LDS -> one atomic/block
    #pragma unroll
    for (int off = 32; off > 0; off >>= 1) lsum += __shfl_down(lsum, off, 64);
    __shared__ float wsum[4];
    const int lane = threadIdx.x & 63;
    const int wid  = threadIdx.x >> 6;
    if (lane == 0) wsum[wid] = lsum;
    __syncthreads();
    if (threadIdx.x == 0) {
        float bs = ((wsum[0] + wsum[1]) + (wsum[2] + wsum[3]));
        // vq_loss = codebk + BETA*commit = 1.25 * mean((z_q - z)^2)
        atomicAdd(out_loss, bs * (1.25f / 4194304.0f));
    }
}

extern "C" void kernel_launch(void* const* d_in, const int* in_sizes, int n_in,
                              void* d_out, int out_size, void* d_ws, size_t ws_size,
                              hipStream_t stream) {
    const float* z  = (const float*)d_in[0];
    const float* cb = (const float*)d_in[1];
    float* out      = (float*)d_out;
    float* out_zq   = out;                    // 4194304 elems
    float* out_loss = out + 4194304;          // 1 elem
    float* out_idx  = out + 4194305;          // 524288 elems (as float values)
    float* pk       = (float*)d_ws;           // 256 pair-records * 20 floats

    hipMemsetAsync(out_loss, 0, sizeof(float), stream);
    prep_pairs<<<1, 256, 0, stream>>>(cb, pk);
    vq_main<<<NPTS / (BLK * PPT), BLK, 0, stream>>>(z, pk, out_zq, out_loss, out_idx);
}